// Round 5
// baseline (339.878 us; speedup 1.0000x reference)
//
#include <hip/hip_runtime.h>

#define DIMK 512
#define NBLK 64
#define NTOK 32768

typedef short  short8 __attribute__((ext_vector_type(8)));
typedef float  f32x4  __attribute__((ext_vector_type(4)));
typedef unsigned short u16x8 __attribute__((ext_vector_type(8)));

__device__ __forceinline__ unsigned short f2bf(float f) {
  union { float f; unsigned u; } v; v.f = f;
  unsigned r = (v.u + 0x7FFFu + ((v.u >> 16) & 1u)) >> 16;   // RNE
  return (unsigned short)r;
}
__device__ __forceinline__ float bf2f(unsigned short h) {
  return __uint_as_float(((unsigned)h) << 16);
}

// ---------------------------------------------------------------------------
// K-slab tiled layouts (all ushort bf16 bits). kk = k&31 throughout.
//   Xb : [(tok>>7)*16 + (k>>5)] [tok&127] [kk]   tile 4096 elem (8 KB)
//   Wt : [w] [k>>5] [n]         [kk]             tile 16384 elem per kt
//   Qb : [(tok>>6)*16 + (k>>5)] [tok&63]  [kk]   tile 2048 elem (4 KB)  (Pb same)
//   Kb : [(tok>>9)*16 + (d>>5)] [tok&511] [kk]   tile 16384 elem (32 KB)
//   Vt : [tok>>5] [d]           [tok&31]         tile 16384 elem (32 KB)
// MFMA fragments are loaded DIRECTLY from these slabs (no LDS staging):
// every fragment is a contiguous 1 KB per wave (l16 -> 64B row stride,
// quad -> 16B chunk), L2-resident, so LDS adds only overhead (r4 analysis:
// K-loops were LDS-read-bound at ~2.5-3.7x the MFMA issue time).
// ---------------------------------------------------------------------------

// ---------------------------------------------------------------------------
// K0 merged prep: [0,8192) xconv | [8192,16384) bitpack | [16384,16576) wt_prep
// ---------------------------------------------------------------------------
__global__ __launch_bounds__(256) void k_prep(
    const float* __restrict__ X, const float* __restrict__ mask,
    const float* __restrict__ dw1, const float* __restrict__ dw2,
    const float* __restrict__ dw3,
    unsigned short* __restrict__ Xb, unsigned char* __restrict__ bits,
    unsigned short* __restrict__ Wt)
{
  __shared__ float t[64][65];
  const int b = blockIdx.x;
  const int tid = threadIdx.x;
  if (b < 8192) {                       // ---- xconv ----
    const size_t gid = (size_t)b * 256 + tid;
    const size_t i = gid * 8;
    const int tok = (int)(i >> 9);
    const int col = (int)(i & 511);
    const float4 a = *(const float4*)(X + i);
    const float4 bb = *(const float4*)(X + i + 4);
    u16x8 o;
    o[0] = f2bf(a.x); o[1] = f2bf(a.y); o[2] = f2bf(a.z); o[3] = f2bf(a.w);
    o[4] = f2bf(bb.x); o[5] = f2bf(bb.y); o[6] = f2bf(bb.z); o[7] = f2bf(bb.w);
    *(u16x8*)(Xb + ((size_t)(tok >> 7) * 16 + (col >> 5)) * 4096 +
              (tok & 127) * 32 + (col & 31)) = o;
  } else if (b < 16384) {               // ---- bitpack ----
    const size_t gid = (size_t)(b - 8192) * 256 + tid;
    const size_t i = gid * 8;
    const float4 ma = *(const float4*)(mask + i);
    const float4 mb = *(const float4*)(mask + i + 4);
    unsigned v = 0;
    v |= (ma.x > 0.5f) << 0; v |= (ma.y > 0.5f) << 1;
    v |= (ma.z > 0.5f) << 2; v |= (ma.w > 0.5f) << 3;
    v |= (mb.x > 0.5f) << 4; v |= (mb.y > 0.5f) << 5;
    v |= (mb.z > 0.5f) << 6; v |= (mb.w > 0.5f) << 7;
    bits[gid] = (unsigned char)v;
  } else {                              // ---- wt_prep ----
    const int bb = b - 16384;
    const int w = bb >> 6;              // 0..2
    const int tt = bb & 63;
    const int kt = (tt >> 3) * 64;
    const int nt = (tt & 7) * 64;
    const float* dw = (w == 0) ? dw1 : (w == 1) ? dw2 : dw3;
    const int rr = tid >> 4;
    const int cc = (tid & 15) << 2;
#pragma unroll
    for (int p = 0; p < 4; ++p) {
      const int r = rr + p * 16;                       // k local
      const float4 v = *(const float4*)&dw[(size_t)(kt + r) * 512 + nt + cc];
      t[cc + 0][r] = v.x; t[cc + 1][r] = v.y;
      t[cc + 2][r] = v.z; t[cc + 3][r] = v.w;          // t[n_local][k_local]
    }
    __syncthreads();
#pragma unroll
    for (int p = 0; p < 4; ++p) {
      const int r = rr + p * 16;                       // n local
      const int n = nt + r;
      const int k = kt + cc;
      ushort4 o;
      o.x = f2bf(t[r][cc + 0]); o.y = f2bf(t[r][cc + 1]);
      o.z = f2bf(t[r][cc + 2]); o.w = f2bf(t[r][cc + 3]);
      *(ushort4*)&Wt[(size_t)w * 262144 + (size_t)(k >> 5) * 16384 +
                     (size_t)n * 32 + (k & 31)] = o;
    }
  }
}

// ---------------------------------------------------------------------------
// K1: merged QKV. Direct-from-global fragment loads (no LDS staging, no loop
// barriers). Per iter: 4 A-frags (Xb slab) + per weight 4 B-frags (Wt slab,
// L2-resident) -> 48 MFMA. LDS only for the V-transpose epilogue.
// ---------------------------------------------------------------------------
__global__ __launch_bounds__(256, 2) void k_qkv(
    const unsigned short* __restrict__ Xb, const unsigned short* __restrict__ Wt,
    const float* __restrict__ db1, const float* __restrict__ db2,
    const float* __restrict__ db3,
    unsigned short* __restrict__ Qb, unsigned short* __restrict__ Kb,
    unsigned short* __restrict__ Vt)
{
  __shared__ __align__(16) unsigned short smem[128 * 136];   // 34 KB epilogue

  const int id = blockIdx.x;
  const int x = id & 7, j = id >> 3;
  const int mtile = x * 32 + (j >> 2);
  const int nt = j & 3;
  const int m0 = mtile * 128;
  const int n0 = nt * 128;

  const int tid = threadIdx.x, lane = tid & 63, wv = tid >> 6;
  const int quad = lane >> 4, l16 = lane & 15;
  const int rb = (wv >> 1) * 64, cb = (wv & 1) * 64;

  f32x4 acc[3][4][4];
#pragma unroll
  for (int w = 0; w < 3; ++w)
#pragma unroll
    for (int i = 0; i < 4; ++i)
#pragma unroll
      for (int jj = 0; jj < 4; ++jj) {
        f32x4 z = {0.f, 0.f, 0.f, 0.f}; acc[w][i][jj] = z;
      }

  for (int it = 0; it < 16; ++it) {
    const unsigned short* aslab = Xb + ((size_t)mtile * 16 + it) * 4096;
    short8 af[4];
#pragma unroll
    for (int i = 0; i < 4; ++i)
      af[i] = *(const short8*)&aslab[(rb + i * 16 + l16) * 32 + quad * 8];
#pragma unroll
    for (int w = 0; w < 3; ++w) {
      const unsigned short* bslab =
          Wt + (size_t)w * 262144 + (size_t)it * 16384 + (size_t)n0 * 32;
      short8 bf[4];
#pragma unroll
      for (int jj = 0; jj < 4; ++jj)
        bf[jj] = *(const short8*)&bslab[(cb + jj * 16 + l16) * 32 + quad * 8];
#pragma unroll
      for (int jj = 0; jj < 4; ++jj)
#pragma unroll
        for (int i = 0; i < 4; ++i)
          acc[w][i][jj] = __builtin_amdgcn_mfma_f32_16x16x32_bf16(
              af[i], bf[jj], acc[w][i][jj], 0, 0, 0);
    }
  }

  // ---- epilogue: Q, K tiled stores ----
#pragma unroll
  for (int i = 0; i < 4; ++i)
#pragma unroll
    for (int jj = 0; jj < 4; ++jj)
#pragma unroll
      for (int r = 0; r < 4; ++r) {
        const int tok = m0 + rb + i * 16 + quad * 4 + r;
        const int col = n0 + cb + jj * 16 + l16;
        Qb[((size_t)(tok >> 6) * 16 + (col >> 5)) * 2048 +
           (tok & 63) * 32 + (col & 31)] = f2bf(acc[0][i][jj][r] + db1[col]);
        Kb[((size_t)(tok >> 9) * 16 + (col >> 5)) * 16384 +
           (tok & 511) * 32 + (col & 31)] = f2bf(acc[1][i][jj][r] + db2[col]);
      }
  // ---- V: LDS transpose (L[col][tok], stride 136) then tiled 16B stores ----
#pragma unroll
  for (int i = 0; i < 4; ++i)
#pragma unroll
    for (int jj = 0; jj < 4; ++jj) {
      const int cl = cb + jj * 16 + l16;          // local col 0..127
      const int t0 = rb + i * 16 + quad * 4;      // local tok 0..127 (x4)
      const float bv = db3[n0 + cl];
      ushort4 pk;
      pk.x = f2bf(acc[2][i][jj][0] + bv);
      pk.y = f2bf(acc[2][i][jj][1] + bv);
      pk.z = f2bf(acc[2][i][jj][2] + bv);
      pk.w = f2bf(acc[2][i][jj][3] + bv);
      *(ushort4*)&smem[cl * 136 + t0] = pk;
    }
  __syncthreads();
#pragma unroll
  for (int h = 0; h < 8; ++h) {
    const int c = tid + h * 256;                  // 2048 16B chunks
    const int cl = c >> 4, toff = (c & 15) * 8;
    const int tg = mtile * 128 + toff;            // global token
    *(u16x8*)&Vt[(size_t)(tg >> 5) * 16384 + (size_t)(n0 + cl) * 32 +
                 (tg & 31)] = *(const u16x8*)&smem[cl * 136 + toff];
  }
}

// ---------------------------------------------------------------------------
// K2: fused scores + mask(bits) + softmax -> P (bf16), P overwrites Q.
// Direct-from-global fragment loads; no LDS in the K-loop, no barriers.
// Grid 512: blk = id & 63 (XCD-coherent), mt = id >> 6.
// ---------------------------------------------------------------------------
__global__ __launch_bounds__(256, 2) void k_attn_p(
    const unsigned short* __restrict__ Qb, const unsigned short* __restrict__ Kb,
    const unsigned long long* __restrict__ bits, unsigned short* __restrict__ Pb)
{
  __shared__ float red[4][64];
  const int tid = threadIdx.x, lane = tid & 63, wv = tid >> 6;
  const int quad = lane >> 4, l16 = lane & 15;
  const int blk = blockIdx.x & 63, mt = blockIdx.x >> 6;
  const size_t q0 = (size_t)blk * 512 + (size_t)mt * 64;
  const int qt = blk * 8 + mt;                 // q0 >> 6

  f32x4 acc[4][8];
#pragma unroll
  for (int i = 0; i < 4; ++i)
#pragma unroll
    for (int j = 0; j < 8; ++j) { f32x4 z = {0.f, 0.f, 0.f, 0.f}; acc[i][j] = z; }

  for (int it = 0; it < 16; ++it) {
    const unsigned short* aslab = Qb + ((size_t)qt * 16 + it) * 2048;
    const unsigned short* bslab = Kb + ((size_t)blk * 16 + it) * 16384;
    short8 af[4], bfv[8];
#pragma unroll
    for (int i = 0; i < 4; ++i)
      af[i] = *(const short8*)&aslab[(i * 16 + l16) * 32 + quad * 8];
#pragma unroll
    for (int j = 0; j < 8; ++j)
      bfv[j] = *(const short8*)&bslab[(wv * 128 + j * 16 + l16) * 32 + quad * 8];
#pragma unroll
    for (int i = 0; i < 4; ++i)
#pragma unroll
      for (int j = 0; j < 8; ++j)
        acc[i][j] = __builtin_amdgcn_mfma_f32_16x16x32_bf16(
            af[i], bfv[j], acc[i][j], 0, 0, 0);
  }

  const float scale = 0.04419417382415922f;   // 1/sqrt(512)
  float rmax[4][4];
#pragma unroll
  for (int i = 0; i < 4; ++i)
#pragma unroll
    for (int r = 0; r < 4; ++r) rmax[i][r] = -3.0e38f;
#pragma unroll
  for (int i = 0; i < 4; ++i)
#pragma unroll
    for (int r = 0; r < 4; ++r) {
      const size_t tok = q0 + i * 16 + quad * 4 + r;
      const unsigned long long w0 = bits[tok * 8 + wv * 2];
      const unsigned long long w1 = bits[tok * 8 + wv * 2 + 1];
#pragma unroll
      for (int j = 0; j < 8; ++j) {
        const unsigned long long sel = (j < 4) ? w0 : w1;
        const float bias = ((sel >> (l16 + 16 * (j & 3))) & 1ull) ? 0.0f : -1e10f;
        const float v = acc[i][j][r] * scale + bias;
        acc[i][j][r] = v;
        rmax[i][r] = fmaxf(rmax[i][r], v);
      }
    }
#pragma unroll
  for (int i = 0; i < 4; ++i)
#pragma unroll
    for (int r = 0; r < 4; ++r)
      for (int d = 1; d < 16; d <<= 1)
        rmax[i][r] = fmaxf(rmax[i][r], __shfl_xor(rmax[i][r], d, 64));
  if (l16 == 0)
#pragma unroll
    for (int i = 0; i < 4; ++i)
#pragma unroll
      for (int r = 0; r < 4; ++r) red[wv][i * 16 + quad * 4 + r] = rmax[i][r];
  __syncthreads();
#pragma unroll
  for (int i = 0; i < 4; ++i)
#pragma unroll
    for (int r = 0; r < 4; ++r) {
      const int row = i * 16 + quad * 4 + r;
      rmax[i][r] = fmaxf(fmaxf(red[0][row], red[1][row]),
                         fmaxf(red[2][row], red[3][row]));
    }
  __syncthreads();
  float rsum[4][4];
#pragma unroll
  for (int i = 0; i < 4; ++i)
#pragma unroll
    for (int r = 0; r < 4; ++r) rsum[i][r] = 0.f;
#pragma unroll
  for (int i = 0; i < 4; ++i)
#pragma unroll
    for (int j = 0; j < 8; ++j)
#pragma unroll
      for (int r = 0; r < 4; ++r) {
        const float e = __expf(acc[i][j][r] - rmax[i][r]);
        acc[i][j][r] = e;
        rsum[i][r] += e;
      }
#pragma unroll
  for (int i = 0; i < 4; ++i)
#pragma unroll
    for (int r = 0; r < 4; ++r)
      for (int d = 1; d < 16; d <<= 1)
        rsum[i][r] += __shfl_xor(rsum[i][r], d, 64);
  if (l16 == 0)
#pragma unroll
    for (int i = 0; i < 4; ++i)
#pragma unroll
      for (int r = 0; r < 4; ++r) red[wv][i * 16 + quad * 4 + r] = rsum[i][r];
  __syncthreads();
#pragma unroll
  for (int i = 0; i < 4; ++i)
#pragma unroll
    for (int r = 0; r < 4; ++r) {
      const int row = i * 16 + quad * 4 + r;
      rsum[i][r] = 1.0f / (red[0][row] + red[1][row] + red[2][row] + red[3][row]);
    }
#pragma unroll
  for (int i = 0; i < 4; ++i)
#pragma unroll
    for (int j = 0; j < 8; ++j)
#pragma unroll
      for (int r = 0; r < 4; ++r) {
        const int tok = (int)(q0 + i * 16 + quad * 4 + r);
        const int col = wv * 128 + j * 16 + l16;
        Pb[((size_t)(tok >> 6) * 16 + (col >> 5)) * 2048 +
           (tok & 63) * 32 + (col & 31)] = f2bf(acc[i][j][r] * rsum[i][r]);
      }
}

// ---------------------------------------------------------------------------
// K3: fused PV + residual(bf16 Xb) + LayerNorm -> Out (fp32).
// Direct-from-global fragment loads; no LDS in the K-loop. Grid 512.
// ---------------------------------------------------------------------------
__global__ __launch_bounds__(256, 2) void k_pv_ln(
    const unsigned short* __restrict__ Pb, const unsigned short* __restrict__ Vt,
    const unsigned short* __restrict__ Xb, float* __restrict__ Out)
{
  __shared__ float2 red[4][64];
  const int tid = threadIdx.x, lane = tid & 63, wv = tid >> 6;
  const int quad = lane >> 4, l16 = lane & 15;
  const int blk = blockIdx.x & 63, mt = blockIdx.x >> 6;
  const size_t q0 = (size_t)blk * 512 + (size_t)mt * 64;
  const int qt = blk * 8 + mt;                 // q0 >> 6

  f32x4 acc[4][8];
#pragma unroll
  for (int i = 0; i < 4; ++i)
#pragma unroll
    for (int j = 0; j < 8; ++j) { f32x4 z = {0.f, 0.f, 0.f, 0.f}; acc[i][j] = z; }

  for (int it = 0; it < 16; ++it) {
    const unsigned short* aslab = Pb + ((size_t)qt * 16 + it) * 2048;
    const unsigned short* bslab = Vt + ((size_t)blk * 16 + it) * 16384;
    short8 af[4], bfv[8];
#pragma unroll
    for (int i = 0; i < 4; ++i)
      af[i] = *(const short8*)&aslab[(i * 16 + l16) * 32 + quad * 8];
#pragma unroll
    for (int j = 0; j < 8; ++j)
      bfv[j] = *(const short8*)&bslab[(wv * 128 + j * 16 + l16) * 32 + quad * 8];
#pragma unroll
    for (int i = 0; i < 4; ++i)
#pragma unroll
      for (int j = 0; j < 8; ++j)
        acc[i][j] = __builtin_amdgcn_mfma_f32_16x16x32_bf16(
            af[i], bfv[j], acc[i][j], 0, 0, 0);
  }

  float vsum[4][4], vsq[4][4];
#pragma unroll
  for (int i = 0; i < 4; ++i)
#pragma unroll
    for (int r = 0; r < 4; ++r) { vsum[i][r] = 0.f; vsq[i][r] = 0.f; }
#pragma unroll
  for (int i = 0; i < 4; ++i)
#pragma unroll
    for (int j = 0; j < 8; ++j)
#pragma unroll
      for (int r = 0; r < 4; ++r) {
        const int tok = (int)(q0 + i * 16 + quad * 4 + r);
        const int col = wv * 128 + j * 16 + l16;
        const float v = acc[i][j][r] +
            bf2f(Xb[((size_t)(tok >> 7) * 16 + (col >> 5)) * 4096 +
                    (tok & 127) * 32 + (col & 31)]);
        acc[i][j][r] = v;
        vsum[i][r] += v;
        vsq[i][r] += v * v;
      }
#pragma unroll
  for (int i = 0; i < 4; ++i)
#pragma unroll
    for (int r = 0; r < 4; ++r)
      for (int d = 1; d < 16; d <<= 1) {
        vsum[i][r] += __shfl_xor(vsum[i][r], d, 64);
        vsq[i][r]  += __shfl_xor(vsq[i][r], d, 64);
      }
  if (l16 == 0)
#pragma unroll
    for (int i = 0; i < 4; ++i)
#pragma unroll
      for (int r = 0; r < 4; ++r) {
        float2 p; p.x = vsum[i][r]; p.y = vsq[i][r];
        red[wv][i * 16 + quad * 4 + r] = p;
      }
  __syncthreads();
#pragma unroll
  for (int i = 0; i < 4; ++i)
#pragma unroll
    for (int r = 0; r < 4; ++r) {
      const int row = i * 16 + quad * 4 + r;
      float s = 0.f, q = 0.f;
#pragma unroll
      for (int w = 0; w < 4; ++w) { s += red[w][row].x; q += red[w][row].y; }
      const float mean = s * (1.0f / 512.0f);
      const float var  = q * (1.0f / 512.0f) - mean * mean;
      vsum[i][r] = mean;
      vsq[i][r]  = rsqrtf(var + 1e-3f);
    }
#pragma unroll
  for (int i = 0; i < 4; ++i)
#pragma unroll
    for (int j = 0; j < 8; ++j)
#pragma unroll
      for (int r = 0; r < 4; ++r) {
        const size_t tok = q0 + i * 16 + quad * 4 + r;
        const int col = wv * 128 + j * 16 + l16;
        Out[tok * (size_t)DIMK + col] =
            (acc[i][j][r] - vsum[i][r]) * vsq[i][r];
      }
}

// ---------------------------------------------------------------------------
extern "C" void kernel_launch(void* const* d_in, const int* in_sizes, int n_in,
                              void* d_out, int out_size, void* d_ws, size_t ws_size,
                              hipStream_t stream)
{
  const float* X    = (const float*)d_in[0];
  const float* mask = (const float*)d_in[1];
  const float* dw1  = (const float*)d_in[2];
  const float* dw2  = (const float*)d_in[3];
  const float* dw3  = (const float*)d_in[4];
  const float* db1  = (const float*)d_in[5];
  const float* db2  = (const float*)d_in[6];
  const float* db3  = (const float*)d_in[7];
  float* Out = (float*)d_out;

  char* ws = (char*)d_ws;
  const size_t MB = 1ull << 20;
  // ws (130 MB): [Wt 2 | Qb/Pb 32 | Kb 32 | Vt 32 | Xb 32]
  // bits (2.1 MB) live in d_out's head: written by k_prep, consumed by
  // k_attn_p, then d_out fully overwritten by k_pv_ln (stream-ordered).
  unsigned short* Wt = (unsigned short*)(ws);
  unsigned short* Qb = (unsigned short*)(ws + 2 * MB);
  unsigned short* Kb = (unsigned short*)(ws + 34 * MB);
  unsigned short* Vt = (unsigned short*)(ws + 66 * MB);
  unsigned short* Xb = (unsigned short*)(ws + 98 * MB);
  unsigned short* Pb = Qb;                      // alias: safe (own-rows only)
  unsigned char*  bits = (unsigned char*)d_out;

  k_prep   <<<16576, 256, 0, stream>>>(X, mask, dw1, dw2, dw3, Xb, bits, Wt);
  k_qkv    <<<1024, 256, 0, stream>>>(Xb, Wt, db1, db2, db3, Qb, Kb, Vt);
  k_attn_p <<<512, 256, 0, stream>>>(Qb, Kb, (const unsigned long long*)bits, Pb);
  k_pv_ln  <<<512, 256, 0, stream>>>(Pb, Vt, Xb, Out);
}

// Round 7
// 294.598 us; speedup vs baseline: 1.1537x; 1.1537x over previous
//
#include <hip/hip_runtime.h>

#define DIMK 512
#define NBLK 64
#define NTOK 32768

typedef short  short8 __attribute__((ext_vector_type(8)));
typedef float  f32x4  __attribute__((ext_vector_type(4)));
typedef unsigned short u16x8 __attribute__((ext_vector_type(8)));

__device__ __forceinline__ unsigned short f2bf(float f) {
  union { float f; unsigned u; } v; v.f = f;
  unsigned r = (v.u + 0x7FFFu + ((v.u >> 16) & 1u)) >> 16;   // RNE
  return (unsigned short)r;
}
__device__ __forceinline__ float bf2f(unsigned short h) {
  return __uint_as_float(((unsigned)h) << 16);
}

// async 16B global -> LDS (wave-uniform base + lane*16)
__device__ __forceinline__ void gload_lds16(const unsigned short* g,
                                            unsigned short* l) {
  __builtin_amdgcn_global_load_lds(
      (const __attribute__((address_space(1))) unsigned int*)(g),
      (__attribute__((address_space(3))) unsigned int*)(l),
      16, 0, 0);
}

// LDS bank swizzle (both-sides, rule 21): logical 16B chunk c (= row*4+col,
// 64B rows) is STORED at c ^ ((c>>3)&3). Stage pre-swizzles the GLOBAL
// source (LDS dest stays linear for global_load_lds); readers use
// qx = quad ^ ((l16>>1)&3). Verified r3: conflicts 4.59M -> 393K.
__device__ __forceinline__ int swz(int c) { return c ^ ((c >> 3) & 3); }

// ---------------------------------------------------------------------------
// K-slab tiled layouts (all ushort bf16 bits). kk = k&31 throughout.
//   Xb : [(tok>>7)*16 + (k>>5)] [tok&127] [kk]   tile 4096 elem (8 KB)
//   Wt : [w] [k>>5] [n]         [kk]             tile 16384 elem per kt
//   Qb : [(tok>>6)*16 + (k>>5)] [tok&63]  [kk]   tile 2048 elem (4 KB)  (Pb same)
//   Kb : [(tok>>9)*16 + (d>>5)] [tok&511] [kk]   tile 16384 elem (32 KB)
//   Vt : [tok>>5] [d]           [tok&31]         tile 16384 elem (32 KB)
// Every GEMM stage read is ONE contiguous slab per K-iteration.
//
// r6 lesson: 512-thr/__launch_bounds__(512,4) demands <=128 VGPR/wave but the
// kernel needs ~230 -> accumulator spill to scratch -> timeout. 8 waves/CU
// (2 blocks x 4 waves, 256 VGPR budget) is the register-feasible maximum.
// r7 change: vectorized epilogues via LDS repack (V-path pattern) — replaces
// 128 scalar global stores/thread with 16-32 coalesced 16B stores.
// ---------------------------------------------------------------------------

// ---------------------------------------------------------------------------
// K0 merged prep: [0,8192) xconv | [8192,16384) bitpack | [16384,16576) wt_prep
// ---------------------------------------------------------------------------
__global__ __launch_bounds__(256) void k_prep(
    const float* __restrict__ X, const float* __restrict__ mask,
    const float* __restrict__ dw1, const float* __restrict__ dw2,
    const float* __restrict__ dw3,
    unsigned short* __restrict__ Xb, unsigned char* __restrict__ bits,
    unsigned short* __restrict__ Wt)
{
  __shared__ float t[64][65];
  const int b = blockIdx.x;
  const int tid = threadIdx.x;
  if (b < 8192) {                       // ---- xconv ----
    const size_t gid = (size_t)b * 256 + tid;
    const size_t i = gid * 8;
    const int tok = (int)(i >> 9);
    const int col = (int)(i & 511);
    const float4 a = *(const float4*)(X + i);
    const float4 bb = *(const float4*)(X + i + 4);
    u16x8 o;
    o[0] = f2bf(a.x); o[1] = f2bf(a.y); o[2] = f2bf(a.z); o[3] = f2bf(a.w);
    o[4] = f2bf(bb.x); o[5] = f2bf(bb.y); o[6] = f2bf(bb.z); o[7] = f2bf(bb.w);
    *(u16x8*)(Xb + ((size_t)(tok >> 7) * 16 + (col >> 5)) * 4096 +
              (tok & 127) * 32 + (col & 31)) = o;
  } else if (b < 16384) {               // ---- bitpack ----
    const size_t gid = (size_t)(b - 8192) * 256 + tid;
    const size_t i = gid * 8;
    const float4 ma = *(const float4*)(mask + i);
    const float4 mb = *(const float4*)(mask + i + 4);
    unsigned v = 0;
    v |= (ma.x > 0.5f) << 0; v |= (ma.y > 0.5f) << 1;
    v |= (ma.z > 0.5f) << 2; v |= (ma.w > 0.5f) << 3;
    v |= (mb.x > 0.5f) << 4; v |= (mb.y > 0.5f) << 5;
    v |= (mb.z > 0.5f) << 6; v |= (mb.w > 0.5f) << 7;
    bits[gid] = (unsigned char)v;
  } else {                              // ---- wt_prep ----
    const int bb = b - 16384;
    const int w = bb >> 6;              // 0..2
    const int tt = bb & 63;
    const int kt = (tt >> 3) * 64;
    const int nt = (tt & 7) * 64;
    const float* dw = (w == 0) ? dw1 : (w == 1) ? dw2 : dw3;
    const int rr = tid >> 4;
    const int cc = (tid & 15) << 2;
#pragma unroll
    for (int p = 0; p < 4; ++p) {
      const int r = rr + p * 16;                       // k local
      const float4 v = *(const float4*)&dw[(size_t)(kt + r) * 512 + nt + cc];
      t[cc + 0][r] = v.x; t[cc + 1][r] = v.y;
      t[cc + 2][r] = v.z; t[cc + 3][r] = v.w;          // t[n_local][k_local]
    }
    __syncthreads();
#pragma unroll
    for (int p = 0; p < 4; ++p) {
      const int r = rr + p * 16;                       // n local
      const int n = nt + r;
      const int k = kt + cc;
      ushort4 o;
      o.x = f2bf(t[r][cc + 0]); o.y = f2bf(t[r][cc + 1]);
      o.z = f2bf(t[r][cc + 2]); o.w = f2bf(t[r][cc + 3]);
      *(ushort4*)&Wt[(size_t)w * 262144 + (size_t)(k >> 5) * 16384 +
                     (size_t)n * 32 + (k & 31)] = o;
    }
  }
}

// ---------------------------------------------------------------------------
// K1: merged QKV (r4-proven: 2-buffer depth-1 pipeline + swizzled LDS,
// 2 blocks/CU). Buffer b at smem + b*16384 elems (As 4096, Bs 3x4096).
// Epilogue: Q,K via LDS repack [128][144] -> u16x8 stores; V via transpose
// tile [col][tok] stride 136 (r4-proven).
// ---------------------------------------------------------------------------
__global__ __launch_bounds__(256, 2) void k_qkv(
    const unsigned short* __restrict__ Xb, const unsigned short* __restrict__ Wt,
    const float* __restrict__ db1, const float* __restrict__ db2,
    const float* __restrict__ db3,
    unsigned short* __restrict__ Qb, unsigned short* __restrict__ Kb,
    unsigned short* __restrict__ Vt)
{
  __shared__ __align__(16) unsigned short smem[32768];   // 64 KB, 2 buffers

  const int id = blockIdx.x;
  const int x = id & 7, j = id >> 3;
  const int mtile = x * 32 + (j >> 2);
  const int nt = j & 3;
  const int m0 = mtile * 128;
  const int n0 = nt * 128;

  const int tid = threadIdx.x, lane = tid & 63, wv = tid >> 6;
  const int quad = lane >> 4, l16 = lane & 15;
  const int qx = quad ^ ((l16 >> 1) & 3);     // swizzled column-chunk
  const int rb = (wv >> 1) * 64, cb = (wv & 1) * 64;

  f32x4 acc[3][4][4];
#pragma unroll
  for (int w = 0; w < 3; ++w)
#pragma unroll
    for (int i = 0; i < 4; ++i)
#pragma unroll
      for (int jj = 0; jj < 4; ++jj) {
        f32x4 z = {0.f, 0.f, 0.f, 0.f}; acc[w][i][jj] = z;
      }

  auto stage = [&](unsigned short* base, int it) {
    const unsigned short* aslab = Xb + ((size_t)mtile * 16 + it) * 4096;
    gload_lds16(aslab + swz(tid) * 8, base + tid * 8);
    gload_lds16(aslab + swz(tid + 256) * 8, base + (tid + 256) * 8);
#pragma unroll
    for (int h = 0; h < 6; ++h) {
      const int c = tid + h * 256;          // 0..1535
      const int w = c >> 9, cc = c & 511;
      const unsigned short* bslab =
          Wt + (size_t)w * 262144 + (size_t)it * 16384 + (size_t)n0 * 32;
      gload_lds16(bslab + swz(cc) * 8, base + 4096 + w * 4096 + cc * 8);
    }
  };

  stage(smem, 0);
  __syncthreads();
  int cur = 0;
  for (int it = 0; it < 16; ++it) {
    unsigned short* cbuf = smem + cur * 16384;
    if (it < 15) stage(smem + (cur ^ 1) * 16384, it + 1);  // prefetch next
    const unsigned short* As = cbuf;
    const unsigned short* Bs = cbuf + 4096;
    short8 af[4];
#pragma unroll
    for (int i = 0; i < 4; ++i)
      af[i] = *(const short8*)&As[(rb + i * 16 + l16) * 32 + qx * 8];
#pragma unroll
    for (int jj = 0; jj < 4; ++jj)
#pragma unroll
      for (int w = 0; w < 3; ++w) {
        const short8 bf =
            *(const short8*)&Bs[w * 4096 + (cb + jj * 16 + l16) * 32 + qx * 8];
#pragma unroll
        for (int i = 0; i < 4; ++i)
          acc[w][i][jj] = __builtin_amdgcn_mfma_f32_16x16x32_bf16(
              af[i], bf, acc[w][i][jj], 0, 0, 0);
      }
    __syncthreads();   // drains vmcnt(0): next buffer fully staged
    cur ^= 1;
  }

  // ---- epilogue: Q, K via LDS repack [tok][col], stride 144 (36 KB) ----
#pragma unroll
  for (int w = 0; w < 2; ++w) {
    __syncthreads();                     // previous pass reads done
    const float* db = (w == 0) ? db1 : db2;
#pragma unroll
    for (int i = 0; i < 4; ++i)
#pragma unroll
      for (int jj = 0; jj < 4; ++jj) {
        const int cl = cb + jj * 16 + l16;
        const float bv = db[n0 + cl];
        const int t0 = rb + i * 16 + quad * 4;
#pragma unroll
        for (int r = 0; r < 4; ++r)
          smem[(t0 + r) * 144 + cl] = f2bf(acc[w][i][jj][r] + bv);
      }
    __syncthreads();
#pragma unroll
    for (int h = 0; h < 8; ++h) {
      const int c = tid + h * 256;       // 2048 16B chunks (128x128 tile)
      const int tl = c >> 4, c0 = (c & 15) * 8;
      const int tokg = m0 + tl, colg = n0 + c0;
      const u16x8 v = *(const u16x8*)&smem[tl * 144 + c0];
      if (w == 0)
        *(u16x8*)&Qb[((size_t)(tokg >> 6) * 16 + (colg >> 5)) * 2048 +
                     (tokg & 63) * 32 + (colg & 31)] = v;
      else
        *(u16x8*)&Kb[((size_t)(tokg >> 9) * 16 + (colg >> 5)) * 16384 +
                     (tokg & 511) * 32 + (colg & 31)] = v;
    }
  }
  // ---- V: LDS transpose (L[col][tok], stride 136) then tiled 16B stores ----
  __syncthreads();
#pragma unroll
  for (int i = 0; i < 4; ++i)
#pragma unroll
    for (int jj = 0; jj < 4; ++jj) {
      const int cl = cb + jj * 16 + l16;          // local col 0..127
      const int t0 = rb + i * 16 + quad * 4;      // local tok 0..127 (x4)
      const float bv = db3[n0 + cl];
      ushort4 pk;
      pk.x = f2bf(acc[2][i][jj][0] + bv);
      pk.y = f2bf(acc[2][i][jj][1] + bv);
      pk.z = f2bf(acc[2][i][jj][2] + bv);
      pk.w = f2bf(acc[2][i][jj][3] + bv);
      *(ushort4*)&smem[cl * 136 + t0] = pk;
    }
  __syncthreads();
#pragma unroll
  for (int h = 0; h < 8; ++h) {
    const int c = tid + h * 256;                  // 2048 16B chunks
    const int cl = c >> 4, toff = (c & 15) * 8;
    const int tg = mtile * 128 + toff;            // global token
    *(u16x8*)&Vt[(size_t)(tg >> 5) * 16384 + (size_t)(n0 + cl) * 32 +
                 (tg & 31)] = *(const u16x8*)&smem[cl * 136 + toff];
  }
}

// ---------------------------------------------------------------------------
// K2: fused scores + mask(bits) + softmax -> P (bf16), P overwrites Q.
// 2-buffer pipeline + swizzled LDS. Epilogue: P via LDS repack [64][528]
// (33.8K elem, fits the 36.9K smem) -> u16x8 stores. Grid 512.
// ---------------------------------------------------------------------------
__global__ __launch_bounds__(256, 2) void k_attn_p(
    const unsigned short* __restrict__ Qb, const unsigned short* __restrict__ Kb,
    const unsigned long long* __restrict__ bits, unsigned short* __restrict__ Pb)
{
  __shared__ __align__(16) unsigned short smem[36864];   // 72 KB, 2 buffers
  __shared__ float red[4][64];
  const int tid = threadIdx.x, lane = tid & 63, wv = tid >> 6;
  const int quad = lane >> 4, l16 = lane & 15;
  const int qx = quad ^ ((l16 >> 1) & 3);
  const int blk = blockIdx.x & 63, mt = blockIdx.x >> 6;
  const size_t q0 = (size_t)blk * 512 + (size_t)mt * 64;
  const int qt = blk * 8 + mt;                 // q0 >> 6

  f32x4 acc[4][8];
#pragma unroll
  for (int i = 0; i < 4; ++i)
#pragma unroll
    for (int j = 0; j < 8; ++j) { f32x4 z = {0.f, 0.f, 0.f, 0.f}; acc[i][j] = z; }

  auto stage = [&](unsigned short* base, int it) {
    const unsigned short* aslab = Qb + ((size_t)qt * 16 + it) * 2048;
    gload_lds16(aslab + swz(tid) * 8, base + tid * 8);
    const unsigned short* bslab = Kb + ((size_t)blk * 16 + it) * 16384;
#pragma unroll
    for (int h = 0; h < 8; ++h) {
      const int c = tid + h * 256;
      gload_lds16(bslab + swz(c) * 8, base + 2048 + c * 8);
    }
  };

  stage(smem, 0);
  __syncthreads();
  int cur = 0;
  for (int it = 0; it < 16; ++it) {
    unsigned short* cbuf = smem + cur * 18432;
    if (it < 15) stage(smem + (cur ^ 1) * 18432, it + 1);
    const unsigned short* As = cbuf;
    const unsigned short* Bs = cbuf + 2048;
    short8 af[4], bfv[8];
#pragma unroll
    for (int i = 0; i < 4; ++i)
      af[i] = *(const short8*)&As[(i * 16 + l16) * 32 + qx * 8];
#pragma unroll
    for (int j = 0; j < 8; ++j)
      bfv[j] = *(const short8*)&Bs[(wv * 128 + j * 16 + l16) * 32 + qx * 8];
#pragma unroll
    for (int i = 0; i < 4; ++i)
#pragma unroll
      for (int j = 0; j < 8; ++j)
        acc[i][j] = __builtin_amdgcn_mfma_f32_16x16x32_bf16(
            af[i], bfv[j], acc[i][j], 0, 0, 0);
    __syncthreads();
    cur ^= 1;
  }

  const float scale = 0.04419417382415922f;   // 1/sqrt(512)
  float rmax[4][4];
#pragma unroll
  for (int i = 0; i < 4; ++i)
#pragma unroll
    for (int r = 0; r < 4; ++r) rmax[i][r] = -3.0e38f;
#pragma unroll
  for (int i = 0; i < 4; ++i)
#pragma unroll
    for (int r = 0; r < 4; ++r) {
      const size_t tok = q0 + i * 16 + quad * 4 + r;
      const unsigned long long w0 = bits[tok * 8 + wv * 2];
      const unsigned long long w1 = bits[tok * 8 + wv * 2 + 1];
#pragma unroll
      for (int j = 0; j < 8; ++j) {
        const unsigned long long sel = (j < 4) ? w0 : w1;
        const float bias = ((sel >> (l16 + 16 * (j & 3))) & 1ull) ? 0.0f : -1e10f;
        const float v = acc[i][j][r] * scale + bias;
        acc[i][j][r] = v;
        rmax[i][r] = fmaxf(rmax[i][r], v);
      }
    }
#pragma unroll
  for (int i = 0; i < 4; ++i)
#pragma unroll
    for (int r = 0; r < 4; ++r)
      for (int d = 1; d < 16; d <<= 1)
        rmax[i][r] = fmaxf(rmax[i][r], __shfl_xor(rmax[i][r], d, 64));
  if (l16 == 0)
#pragma unroll
    for (int i = 0; i < 4; ++i)
#pragma unroll
      for (int r = 0; r < 4; ++r) red[wv][i * 16 + quad * 4 + r] = rmax[i][r];
  __syncthreads();
#pragma unroll
  for (int i = 0; i < 4; ++i)
#pragma unroll
    for (int r = 0; r < 4; ++r) {
      const int row = i * 16 + quad * 4 + r;
      rmax[i][r] = fmaxf(fmaxf(red[0][row], red[1][row]),
                         fmaxf(red[2][row], red[3][row]));
    }
  __syncthreads();
  float rsum[4][4];
#pragma unroll
  for (int i = 0; i < 4; ++i)
#pragma unroll
    for (int r = 0; r < 4; ++r) rsum[i][r] = 0.f;
#pragma unroll
  for (int i = 0; i < 4; ++i)
#pragma unroll
    for (int j = 0; j < 8; ++j)
#pragma unroll
      for (int r = 0; r < 4; ++r) {
        const float e = __expf(acc[i][j][r] - rmax[i][r]);
        acc[i][j][r] = e;
        rsum[i][r] += e;
      }
#pragma unroll
  for (int i = 0; i < 4; ++i)
#pragma unroll
    for (int r = 0; r < 4; ++r)
      for (int d = 1; d < 16; d <<= 1)
        rsum[i][r] += __shfl_xor(rsum[i][r], d, 64);
  if (l16 == 0)
#pragma unroll
    for (int i = 0; i < 4; ++i)
#pragma unroll
      for (int r = 0; r < 4; ++r) red[wv][i * 16 + quad * 4 + r] = rsum[i][r];
  __syncthreads();
#pragma unroll
  for (int i = 0; i < 4; ++i)
#pragma unroll
    for (int r = 0; r < 4; ++r) {
      const int row = i * 16 + quad * 4 + r;
      rsum[i][r] = 1.0f / (red[0][row] + red[1][row] + red[2][row] + red[3][row]);
    }
  // ---- P repack: L[64][528] overlays dead stage buffers -> u16x8 stores ----
#pragma unroll
  for (int i = 0; i < 4; ++i)
#pragma unroll
    for (int j = 0; j < 8; ++j) {
      const int cl = wv * 128 + j * 16 + l16;
      const int t0 = i * 16 + quad * 4;
#pragma unroll
      for (int r = 0; r < 4; ++r)
        smem[(t0 + r) * 528 + cl] = f2bf(acc[i][j][r] * rsum[i][r]);
    }
  __syncthreads();
#pragma unroll
  for (int h = 0; h < 16; ++h) {
    const int c = tid + h * 256;             // 4096 16B chunks (64x512)
    const int tl = c >> 6, c0 = (c & 63) * 8;
    const int tokg = (int)q0 + tl;
    const u16x8 v = *(const u16x8*)&smem[tl * 528 + c0];
    *(u16x8*)&Pb[((size_t)(tokg >> 6) * 16 + (c0 >> 5)) * 2048 +
                 (tokg & 63) * 32 + (c0 & 31)] = v;
  }
}

// ---------------------------------------------------------------------------
// K3: fused PV + residual(bf16 Xb) + LayerNorm -> Out (fp32).
// 2-buffer pipeline + swizzled LDS. Epilogue: Out via LDS repack
// float[64][264] in two col-halves -> float4 stores. Grid 512.
// ---------------------------------------------------------------------------
__global__ __launch_bounds__(256, 2) void k_pv_ln(
    const unsigned short* __restrict__ Pb, const unsigned short* __restrict__ Vt,
    const unsigned short* __restrict__ Xb, float* __restrict__ Out)
{
  __shared__ __align__(16) unsigned short smem[36864];   // 72 KB, 2 buffers
  __shared__ float2 red[4][64];
  const int tid = threadIdx.x, lane = tid & 63, wv = tid >> 6;
  const int quad = lane >> 4, l16 = lane & 15;
  const int qx = quad ^ ((l16 >> 1) & 3);
  const int blk = blockIdx.x & 63, mt = blockIdx.x >> 6;
  const size_t q0 = (size_t)blk * 512 + (size_t)mt * 64;
  const int qt = blk * 8 + mt;                 // q0 >> 6

  f32x4 acc[4][8];
#pragma unroll
  for (int i = 0; i < 4; ++i)
#pragma unroll
    for (int j = 0; j < 8; ++j) { f32x4 z = {0.f, 0.f, 0.f, 0.f}; acc[i][j] = z; }

  auto stage = [&](unsigned short* base, int it) {
    const unsigned short* aslab = Pb + ((size_t)qt * 16 + it) * 2048;
    gload_lds16(aslab + swz(tid) * 8, base + tid * 8);
    const unsigned short* bslab = Vt + ((size_t)blk * 16 + it) * 16384;
#pragma unroll
    for (int h = 0; h < 8; ++h) {
      const int c = tid + h * 256;
      gload_lds16(bslab + swz(c) * 8, base + 2048 + c * 8);
    }
  };

  stage(smem, 0);
  __syncthreads();
  int cur = 0;
  for (int it = 0; it < 16; ++it) {
    unsigned short* cbuf = smem + cur * 18432;
    if (it < 15) stage(smem + (cur ^ 1) * 18432, it + 1);
    const unsigned short* As = cbuf;
    const unsigned short* Bs = cbuf + 2048;
    short8 af[4], bfv[8];
#pragma unroll
    for (int i = 0; i < 4; ++i)
      af[i] = *(const short8*)&As[(i * 16 + l16) * 32 + qx * 8];
#pragma unroll
    for (int j = 0; j < 8; ++j)
      bfv[j] = *(const short8*)&Bs[(wv * 128 + j * 16 + l16) * 32 + qx * 8];
#pragma unroll
    for (int i = 0; i < 4; ++i)
#pragma unroll
      for (int j = 0; j < 8; ++j)
        acc[i][j] = __builtin_amdgcn_mfma_f32_16x16x32_bf16(
            af[i], bfv[j], acc[i][j], 0, 0, 0);
    __syncthreads();
    cur ^= 1;
  }

  float vsum[4][4], vsq[4][4];
#pragma unroll
  for (int i = 0; i < 4; ++i)
#pragma unroll
    for (int r = 0; r < 4; ++r) { vsum[i][r] = 0.f; vsq[i][r] = 0.f; }
#pragma unroll
  for (int i = 0; i < 4; ++i)
#pragma unroll
    for (int j = 0; j < 8; ++j)
#pragma unroll
      for (int r = 0; r < 4; ++r) {
        const int tok = (int)(q0 + i * 16 + quad * 4 + r);
        const int col = wv * 128 + j * 16 + l16;
        const float v = acc[i][j][r] +
            bf2f(Xb[((size_t)(tok >> 7) * 16 + (col >> 5)) * 4096 +
                    (tok & 127) * 32 + (col & 31)]);
        acc[i][j][r] = v;
        vsum[i][r] += v;
        vsq[i][r] += v * v;
      }
#pragma unroll
  for (int i = 0; i < 4; ++i)
#pragma unroll
    for (int r = 0; r < 4; ++r)
      for (int d = 1; d < 16; d <<= 1) {
        vsum[i][r] += __shfl_xor(vsum[i][r], d, 64);
        vsq[i][r]  += __shfl_xor(vsq[i][r], d, 64);
      }
  if (l16 == 0)
#pragma unroll
    for (int i = 0; i < 4; ++i)
#pragma unroll
      for (int r = 0; r < 4; ++r) {
        float2 p; p.x = vsum[i][r]; p.y = vsq[i][r];
        red[wv][i * 16 + quad * 4 + r] = p;
      }
  __syncthreads();
#pragma unroll
  for (int i = 0; i < 4; ++i)
#pragma unroll
    for (int r = 0; r < 4; ++r) {
      const int row = i * 16 + quad * 4 + r;
      float s = 0.f, q = 0.f;
#pragma unroll
      for (int w = 0; w < 4; ++w) { s += red[w][row].x; q += red[w][row].y; }
      const float mean = s * (1.0f / 512.0f);
      const float var  = q * (1.0f / 512.0f) - mean * mean;
      vsum[i][r] = mean;
      vsq[i][r]  = rsqrtf(var + 1e-3f);
    }
  // ---- Out repack: float L[64][264] (66 KB), two col-halves ----
  float* L = (float*)smem;
#pragma unroll
  for (int p = 0; p < 2; ++p) {
    __syncthreads();                       // previous pass reads done
    if ((wv >> 1) == p) {                  // waves owning cols [p*256, p*256+256)
#pragma unroll
      for (int i = 0; i < 4; ++i)
#pragma unroll
        for (int j = 0; j < 8; ++j) {
          const int cl = (wv & 1) * 128 + j * 16 + l16;
          const int t0 = i * 16 + quad * 4;
#pragma unroll
          for (int r = 0; r < 4; ++r)
            L[(t0 + r) * 264 + cl] = (acc[i][j][r] - vsum[i][r]) * vsq[i][r];
        }
    }
    __syncthreads();
#pragma unroll
    for (int h = 0; h < 16; ++h) {
      const int c = tid + h * 256;         // 4096 float4 chunks (64x256)
      const int tl = c >> 6, c0 = (c & 63) * 4;
      const float4 v = *(const float4*)&L[tl * 264 + c0];
      *(float4*)&Out[(q0 + tl) * (size_t)DIMK + p * 256 + c0] = v;
    }
  }
}

// ---------------------------------------------------------------------------
extern "C" void kernel_launch(void* const* d_in, const int* in_sizes, int n_in,
                              void* d_out, int out_size, void* d_ws, size_t ws_size,
                              hipStream_t stream)
{
  const float* X    = (const float*)d_in[0];
  const float* mask = (const float*)d_in[1];
  const float* dw1  = (const float*)d_in[2];
  const float* dw2  = (const float*)d_in[3];
  const float* dw3  = (const float*)d_in[4];
  const float* db1  = (const float*)d_in[5];
  const float* db2  = (const float*)d_in[6];
  const float* db3  = (const float*)d_in[7];
  float* Out = (float*)d_out;

  char* ws = (char*)d_ws;
  const size_t MB = 1ull << 20;
  // ws (130 MB): [Wt 2 | Qb/Pb 32 | Kb 32 | Vt 32 | Xb 32]
  // bits (2.1 MB) live in d_out's head: written by k_prep, consumed by
  // k_attn_p, then d_out fully overwritten by k_pv_ln (stream-ordered).
  unsigned short* Wt = (unsigned short*)(ws);
  unsigned short* Qb = (unsigned short*)(ws + 2 * MB);
  unsigned short* Kb = (unsigned short*)(ws + 34 * MB);
  unsigned short* Vt = (unsigned short*)(ws + 66 * MB);
  unsigned short* Xb = (unsigned short*)(ws + 98 * MB);
  unsigned short* Pb = Qb;                      // alias: safe (own-rows only)
  unsigned char*  bits = (unsigned char*)d_out;

  k_prep   <<<16576, 256, 0, stream>>>(X, mask, dw1, dw2, dw3, Xb, bits, Wt);
  k_qkv    <<<1024, 256, 0, stream>>>(Xb, Wt, db1, db2, db3, Qb, Kb, Vt);
  k_attn_p <<<512, 256, 0, stream>>>(Qb, Kb, (const unsigned long long*)bits, Pb);
  k_pv_ln  <<<512, 256, 0, stream>>>(Pb, Vt, Xb, Out);
}

// Round 8
// 291.869 us; speedup vs baseline: 1.1645x; 1.0094x over previous
//
#include <hip/hip_runtime.h>

#define DIMK 512
#define NBLK 64
#define NTOK 32768

typedef short  short8 __attribute__((ext_vector_type(8)));
typedef float  f32x4  __attribute__((ext_vector_type(4)));
typedef unsigned short u16x8 __attribute__((ext_vector_type(8)));

__device__ __forceinline__ unsigned short f2bf(float f) {
  union { float f; unsigned u; } v; v.f = f;
  unsigned r = (v.u + 0x7FFFu + ((v.u >> 16) & 1u)) >> 16;   // RNE
  return (unsigned short)r;
}
__device__ __forceinline__ float bf2f(unsigned short h) {
  return __uint_as_float(((unsigned)h) << 16);
}

// async 16B global -> LDS (wave-uniform base + lane*16)
__device__ __forceinline__ void gload_lds16(const unsigned short* g,
                                            unsigned short* l) {
  __builtin_amdgcn_global_load_lds(
      (const __attribute__((address_space(1))) unsigned int*)(g),
      (__attribute__((address_space(3))) unsigned int*)(l),
      16, 0, 0);
}

// LDS bank swizzle (both-sides, rule 21): logical 16B chunk c (= row*4+col,
// 64B rows) is STORED at c ^ ((c>>3)&3). Stage pre-swizzles the GLOBAL
// source (LDS dest stays linear for global_load_lds); readers use
// qx = quad ^ ((l16>>1)&3). Verified r3: conflicts 4.59M -> 393K.
__device__ __forceinline__ int swz(int c) { return c ^ ((c >> 3) & 3); }

// ---------------------------------------------------------------------------
// K-slab tiled layouts (all ushort bf16 bits). kk = k&31 throughout.
//   Xb : [(tok>>7)*16 + (k>>5)] [tok&127] [kk]   tile 4096 elem (8 KB)
//   Wt : [w] [k>>5] [n]         [kk]             tile 16384 elem per kt
//   Qb : [(tok>>6)*16 + (k>>5)] [tok&63]  [kk]   tile 2048 elem (4 KB)  (Pb same)
//   Kb : [(tok>>9)*16 + (d>>5)] [tok&511] [kk]   tile 16384 elem (32 KB)
//   Vt : [tok>>5] [d]           [tok&31]         tile 16384 elem (32 KB)
// Every GEMM stage read is ONE contiguous slab per K-iteration.
//
// XCD locality (r8): k_qkv block x=id&7 runs on XCD x and produces K/V/Q for
// attention-blocks blk in [8x, 8x+8)  (producer XCD = blk>>3). K2/K3 decode
// blk = (id&7)*8 + ((id>>3)&7) so consumer XCD == blk>>3 == producer XCD:
// K/V/P slabs (512 KB/blk) stay in the local 4 MB L2 instead of bouncing
// through L3 (stage-miss latency ~900 -> ~200 cyc).
// r7 lesson: Q/K repack writes at stride 144 had quad*4*72 mod 32 == 0 ->
// 4-8-way bank conflicts (393K -> 1.70M), k_qkv 60.1 -> 62.5 us. Reverted.
// ---------------------------------------------------------------------------

// ---------------------------------------------------------------------------
// K0 merged prep: [0,8192) xconv | [8192,16384) bitpack | [16384,16576) wt_prep
// ---------------------------------------------------------------------------
__global__ __launch_bounds__(256) void k_prep(
    const float* __restrict__ X, const float* __restrict__ mask,
    const float* __restrict__ dw1, const float* __restrict__ dw2,
    const float* __restrict__ dw3,
    unsigned short* __restrict__ Xb, unsigned char* __restrict__ bits,
    unsigned short* __restrict__ Wt)
{
  __shared__ float t[64][65];
  const int b = blockIdx.x;
  const int tid = threadIdx.x;
  if (b < 8192) {                       // ---- xconv ----
    const size_t gid = (size_t)b * 256 + tid;
    const size_t i = gid * 8;
    const int tok = (int)(i >> 9);
    const int col = (int)(i & 511);
    const float4 a = *(const float4*)(X + i);
    const float4 bb = *(const float4*)(X + i + 4);
    u16x8 o;
    o[0] = f2bf(a.x); o[1] = f2bf(a.y); o[2] = f2bf(a.z); o[3] = f2bf(a.w);
    o[4] = f2bf(bb.x); o[5] = f2bf(bb.y); o[6] = f2bf(bb.z); o[7] = f2bf(bb.w);
    *(u16x8*)(Xb + ((size_t)(tok >> 7) * 16 + (col >> 5)) * 4096 +
              (tok & 127) * 32 + (col & 31)) = o;
  } else if (b < 16384) {               // ---- bitpack ----
    const size_t gid = (size_t)(b - 8192) * 256 + tid;
    const size_t i = gid * 8;
    const float4 ma = *(const float4*)(mask + i);
    const float4 mb = *(const float4*)(mask + i + 4);
    unsigned v = 0;
    v |= (ma.x > 0.5f) << 0; v |= (ma.y > 0.5f) << 1;
    v |= (ma.z > 0.5f) << 2; v |= (ma.w > 0.5f) << 3;
    v |= (mb.x > 0.5f) << 4; v |= (mb.y > 0.5f) << 5;
    v |= (mb.z > 0.5f) << 6; v |= (mb.w > 0.5f) << 7;
    bits[gid] = (unsigned char)v;
  } else {                              // ---- wt_prep ----
    const int bb = b - 16384;
    const int w = bb >> 6;              // 0..2
    const int tt = bb & 63;
    const int kt = (tt >> 3) * 64;
    const int nt = (tt & 7) * 64;
    const float* dw = (w == 0) ? dw1 : (w == 1) ? dw2 : dw3;
    const int rr = tid >> 4;
    const int cc = (tid & 15) << 2;
#pragma unroll
    for (int p = 0; p < 4; ++p) {
      const int r = rr + p * 16;                       // k local
      const float4 v = *(const float4*)&dw[(size_t)(kt + r) * 512 + nt + cc];
      t[cc + 0][r] = v.x; t[cc + 1][r] = v.y;
      t[cc + 2][r] = v.z; t[cc + 3][r] = v.w;          // t[n_local][k_local]
    }
    __syncthreads();
#pragma unroll
    for (int p = 0; p < 4; ++p) {
      const int r = rr + p * 16;                       // n local
      const int n = nt + r;
      const int k = kt + cc;
      ushort4 o;
      o.x = f2bf(t[r][cc + 0]); o.y = f2bf(t[r][cc + 1]);
      o.z = f2bf(t[r][cc + 2]); o.w = f2bf(t[r][cc + 3]);
      *(ushort4*)&Wt[(size_t)w * 262144 + (size_t)(k >> 5) * 16384 +
                     (size_t)n * 32 + (k & 31)] = o;
    }
  }
}

// ---------------------------------------------------------------------------
// K1: merged QKV (r4-proven: 2-buffer depth-1 pipeline + swizzled LDS,
// 2 blocks/CU, direct scalar Q/K stores). Buffer b at smem + b*16384 elems
// (As 4096, Bs 3x4096). Epilogue V-transpose reuses smem[0, 128*136).
// ---------------------------------------------------------------------------
__global__ __launch_bounds__(256, 2) void k_qkv(
    const unsigned short* __restrict__ Xb, const unsigned short* __restrict__ Wt,
    const float* __restrict__ db1, const float* __restrict__ db2,
    const float* __restrict__ db3,
    unsigned short* __restrict__ Qb, unsigned short* __restrict__ Kb,
    unsigned short* __restrict__ Vt)
{
  __shared__ __align__(16) unsigned short smem[32768];   // 64 KB, 2 buffers

  const int id = blockIdx.x;
  const int x = id & 7, j = id >> 3;
  const int mtile = x * 32 + (j >> 2);
  const int nt = j & 3;
  const int m0 = mtile * 128;
  const int n0 = nt * 128;

  const int tid = threadIdx.x, lane = tid & 63, wv = tid >> 6;
  const int quad = lane >> 4, l16 = lane & 15;
  const int qx = quad ^ ((l16 >> 1) & 3);     // swizzled column-chunk
  const int rb = (wv >> 1) * 64, cb = (wv & 1) * 64;

  f32x4 acc[3][4][4];
#pragma unroll
  for (int w = 0; w < 3; ++w)
#pragma unroll
    for (int i = 0; i < 4; ++i)
#pragma unroll
      for (int jj = 0; jj < 4; ++jj) {
        f32x4 z = {0.f, 0.f, 0.f, 0.f}; acc[w][i][jj] = z;
      }

  auto stage = [&](unsigned short* base, int it) {
    const unsigned short* aslab = Xb + ((size_t)mtile * 16 + it) * 4096;
    gload_lds16(aslab + swz(tid) * 8, base + tid * 8);
    gload_lds16(aslab + swz(tid + 256) * 8, base + (tid + 256) * 8);
#pragma unroll
    for (int h = 0; h < 6; ++h) {
      const int c = tid + h * 256;          // 0..1535
      const int w = c >> 9, cc = c & 511;
      const unsigned short* bslab =
          Wt + (size_t)w * 262144 + (size_t)it * 16384 + (size_t)n0 * 32;
      gload_lds16(bslab + swz(cc) * 8, base + 4096 + w * 4096 + cc * 8);
    }
  };

  stage(smem, 0);
  __syncthreads();
  int cur = 0;
  for (int it = 0; it < 16; ++it) {
    unsigned short* cbuf = smem + cur * 16384;
    if (it < 15) stage(smem + (cur ^ 1) * 16384, it + 1);  // prefetch next
    const unsigned short* As = cbuf;
    const unsigned short* Bs = cbuf + 4096;
    short8 af[4];
#pragma unroll
    for (int i = 0; i < 4; ++i)
      af[i] = *(const short8*)&As[(rb + i * 16 + l16) * 32 + qx * 8];
#pragma unroll
    for (int jj = 0; jj < 4; ++jj)
#pragma unroll
      for (int w = 0; w < 3; ++w) {
        const short8 bf =
            *(const short8*)&Bs[w * 4096 + (cb + jj * 16 + l16) * 32 + qx * 8];
#pragma unroll
        for (int i = 0; i < 4; ++i)
          acc[w][i][jj] = __builtin_amdgcn_mfma_f32_16x16x32_bf16(
              af[i], bf, acc[w][i][jj], 0, 0, 0);
      }
    __syncthreads();   // drains vmcnt(0): next buffer fully staged
    cur ^= 1;
  }

  // ---- epilogue: Q, K tiled stores (direct; r4-proven) ----
#pragma unroll
  for (int i = 0; i < 4; ++i)
#pragma unroll
    for (int jj = 0; jj < 4; ++jj)
#pragma unroll
      for (int r = 0; r < 4; ++r) {
        const int tok = m0 + rb + i * 16 + quad * 4 + r;
        const int col = n0 + cb + jj * 16 + l16;
        Qb[((size_t)(tok >> 6) * 16 + (col >> 5)) * 2048 +
           (tok & 63) * 32 + (col & 31)] = f2bf(acc[0][i][jj][r] + db1[col]);
        Kb[((size_t)(tok >> 9) * 16 + (col >> 5)) * 16384 +
           (tok & 511) * 32 + (col & 31)] = f2bf(acc[1][i][jj][r] + db2[col]);
      }
  // ---- V: LDS transpose (L[col][tok], stride 136) then tiled 16B stores ----
#pragma unroll
  for (int i = 0; i < 4; ++i)
#pragma unroll
    for (int jj = 0; jj < 4; ++jj) {
      const int cl = cb + jj * 16 + l16;          // local col 0..127
      const int t0 = rb + i * 16 + quad * 4;      // local tok 0..127 (x4)
      const float bv = db3[n0 + cl];
      ushort4 pk;
      pk.x = f2bf(acc[2][i][jj][0] + bv);
      pk.y = f2bf(acc[2][i][jj][1] + bv);
      pk.z = f2bf(acc[2][i][jj][2] + bv);
      pk.w = f2bf(acc[2][i][jj][3] + bv);
      *(ushort4*)&smem[cl * 136 + t0] = pk;
    }
  __syncthreads();
#pragma unroll
  for (int h = 0; h < 8; ++h) {
    const int c = tid + h * 256;                  // 2048 16B chunks
    const int cl = c >> 4, toff = (c & 15) * 8;
    const int tg = mtile * 128 + toff;            // global token
    *(u16x8*)&Vt[(size_t)(tg >> 5) * 16384 + (size_t)(n0 + cl) * 32 +
                 (tg & 31)] = *(const u16x8*)&smem[cl * 136 + toff];
  }
}

// ---------------------------------------------------------------------------
// K2: fused scores + mask(bits) + softmax -> P (bf16), P overwrites Q.
// 2-buffer pipeline + swizzled LDS. XCD-aligned decode (consumer XCD =
// producer XCD = blk>>3). Epilogue: P via LDS repack [64][520] -> u16x8.
// Grid 512.
// ---------------------------------------------------------------------------
__global__ __launch_bounds__(256, 2) void k_attn_p(
    const unsigned short* __restrict__ Qb, const unsigned short* __restrict__ Kb,
    const unsigned long long* __restrict__ bits, unsigned short* __restrict__ Pb)
{
  __shared__ __align__(16) unsigned short smem[36864];   // 72 KB, 2 buffers
  __shared__ float red[4][64];
  const int tid = threadIdx.x, lane = tid & 63, wv = tid >> 6;
  const int quad = lane >> 4, l16 = lane & 15;
  const int qx = quad ^ ((l16 >> 1) & 3);
  const int id = blockIdx.x;
  const int blk = (id & 7) * 8 + ((id >> 3) & 7);   // XCD(id)=id&7 == blk>>3
  const int mt = id >> 6;
  const size_t q0 = (size_t)blk * 512 + (size_t)mt * 64;
  const int qt = blk * 8 + mt;                 // q0 >> 6

  f32x4 acc[4][8];
#pragma unroll
  for (int i = 0; i < 4; ++i)
#pragma unroll
    for (int j = 0; j < 8; ++j) { f32x4 z = {0.f, 0.f, 0.f, 0.f}; acc[i][j] = z; }

  auto stage = [&](unsigned short* base, int it) {
    const unsigned short* aslab = Qb + ((size_t)qt * 16 + it) * 2048;
    gload_lds16(aslab + swz(tid) * 8, base + tid * 8);
    const unsigned short* bslab = Kb + ((size_t)blk * 16 + it) * 16384;
#pragma unroll
    for (int h = 0; h < 8; ++h) {
      const int c = tid + h * 256;
      gload_lds16(bslab + swz(c) * 8, base + 2048 + c * 8);
    }
  };

  stage(smem, 0);
  __syncthreads();
  int cur = 0;
  for (int it = 0; it < 16; ++it) {
    unsigned short* cbuf = smem + cur * 18432;
    if (it < 15) stage(smem + (cur ^ 1) * 18432, it + 1);
    const unsigned short* As = cbuf;
    const unsigned short* Bs = cbuf + 2048;
    short8 af[4], bfv[8];
#pragma unroll
    for (int i = 0; i < 4; ++i)
      af[i] = *(const short8*)&As[(i * 16 + l16) * 32 + qx * 8];
#pragma unroll
    for (int j = 0; j < 8; ++j)
      bfv[j] = *(const short8*)&Bs[(wv * 128 + j * 16 + l16) * 32 + qx * 8];
#pragma unroll
    for (int i = 0; i < 4; ++i)
#pragma unroll
      for (int j = 0; j < 8; ++j)
        acc[i][j] = __builtin_amdgcn_mfma_f32_16x16x32_bf16(
            af[i], bfv[j], acc[i][j], 0, 0, 0);
    __syncthreads();
    cur ^= 1;
  }

  const float scale = 0.04419417382415922f;   // 1/sqrt(512)
  float rmax[4][4];
#pragma unroll
  for (int i = 0; i < 4; ++i)
#pragma unroll
    for (int r = 0; r < 4; ++r) rmax[i][r] = -3.0e38f;
#pragma unroll
  for (int i = 0; i < 4; ++i)
#pragma unroll
    for (int r = 0; r < 4; ++r) {
      const size_t tok = q0 + i * 16 + quad * 4 + r;
      const unsigned long long w0 = bits[tok * 8 + wv * 2];
      const unsigned long long w1 = bits[tok * 8 + wv * 2 + 1];
#pragma unroll
      for (int j = 0; j < 8; ++j) {
        const unsigned long long sel = (j < 4) ? w0 : w1;
        const float bias = ((sel >> (l16 + 16 * (j & 3))) & 1ull) ? 0.0f : -1e10f;
        const float v = acc[i][j][r] * scale + bias;
        acc[i][j][r] = v;
        rmax[i][r] = fmaxf(rmax[i][r], v);
      }
    }
#pragma unroll
  for (int i = 0; i < 4; ++i)
#pragma unroll
    for (int r = 0; r < 4; ++r)
      for (int d = 1; d < 16; d <<= 1)
        rmax[i][r] = fmaxf(rmax[i][r], __shfl_xor(rmax[i][r], d, 64));
  if (l16 == 0)
#pragma unroll
    for (int i = 0; i < 4; ++i)
#pragma unroll
      for (int r = 0; r < 4; ++r) red[wv][i * 16 + quad * 4 + r] = rmax[i][r];
  __syncthreads();
#pragma unroll
  for (int i = 0; i < 4; ++i)
#pragma unroll
    for (int r = 0; r < 4; ++r) {
      const int row = i * 16 + quad * 4 + r;
      rmax[i][r] = fmaxf(fmaxf(red[0][row], red[1][row]),
                         fmaxf(red[2][row], red[3][row]));
    }
  __syncthreads();
  float rsum[4][4];
#pragma unroll
  for (int i = 0; i < 4; ++i)
#pragma unroll
    for (int r = 0; r < 4; ++r) rsum[i][r] = 0.f;
#pragma unroll
  for (int i = 0; i < 4; ++i)
#pragma unroll
    for (int j = 0; j < 8; ++j)
#pragma unroll
      for (int r = 0; r < 4; ++r) {
        const float e = __expf(acc[i][j][r] - rmax[i][r]);
        acc[i][j][r] = e;
        rsum[i][r] += e;
      }
#pragma unroll
  for (int i = 0; i < 4; ++i)
#pragma unroll
    for (int r = 0; r < 4; ++r)
      for (int d = 1; d < 16; d <<= 1)
        rsum[i][r] += __shfl_xor(rsum[i][r], d, 64);
  if (l16 == 0)
#pragma unroll
    for (int i = 0; i < 4; ++i)
#pragma unroll
      for (int r = 0; r < 4; ++r) red[wv][i * 16 + quad * 4 + r] = rsum[i][r];
  __syncthreads();
#pragma unroll
  for (int i = 0; i < 4; ++i)
#pragma unroll
    for (int r = 0; r < 4; ++r) {
      const int row = i * 16 + quad * 4 + r;
      rsum[i][r] = 1.0f / (red[0][row] + red[1][row] + red[2][row] + red[3][row]);
    }
  // ---- P repack: L[64][520] (stride 520: 2*520 mod 32 != 0 spreads quads,
  // 16B-aligned rows) -> u16x8 stores ----
#pragma unroll
  for (int i = 0; i < 4; ++i)
#pragma unroll
    for (int j = 0; j < 8; ++j) {
      const int cl = wv * 128 + j * 16 + l16;
      const int t0 = i * 16 + quad * 4;
#pragma unroll
      for (int r = 0; r < 4; ++r)
        smem[(t0 + r) * 520 + cl] = f2bf(acc[i][j][r] * rsum[i][r]);
    }
  __syncthreads();
#pragma unroll
  for (int h = 0; h < 16; ++h) {
    const int c = tid + h * 256;             // 4096 16B chunks (64x512)
    const int tl = c >> 6, c0 = (c & 63) * 8;
    const int tokg = (int)q0 + tl;
    const u16x8 v = *(const u16x8*)&smem[tl * 520 + c0];
    *(u16x8*)&Pb[((size_t)(tokg >> 6) * 16 + (c0 >> 5)) * 2048 +
                 (tokg & 63) * 32 + (c0 & 31)] = v;
  }
}

// ---------------------------------------------------------------------------
// K3: fused PV + residual(bf16 Xb) + LayerNorm -> Out (fp32).
// 2-buffer pipeline + swizzled LDS, XCD-aligned decode. Epilogue: Out via
// LDS repack float[64][260] in two col-halves -> float4 stores. Grid 512.
// ---------------------------------------------------------------------------
__global__ __launch_bounds__(256, 2) void k_pv_ln(
    const unsigned short* __restrict__ Pb, const unsigned short* __restrict__ Vt,
    const unsigned short* __restrict__ Xb, float* __restrict__ Out)
{
  __shared__ __align__(16) unsigned short smem[36864];   // 72 KB, 2 buffers
  __shared__ float2 red[4][64];
  const int tid = threadIdx.x, lane = tid & 63, wv = tid >> 6;
  const int quad = lane >> 4, l16 = lane & 15;
  const int qx = quad ^ ((l16 >> 1) & 3);
  const int id = blockIdx.x;
  const int blk = (id & 7) * 8 + ((id >> 3) & 7);   // XCD(id)=id&7 == blk>>3
  const int mt = id >> 6;
  const size_t q0 = (size_t)blk * 512 + (size_t)mt * 64;
  const int qt = blk * 8 + mt;                 // q0 >> 6

  f32x4 acc[4][8];
#pragma unroll
  for (int i = 0; i < 4; ++i)
#pragma unroll
    for (int j = 0; j < 8; ++j) { f32x4 z = {0.f, 0.f, 0.f, 0.f}; acc[i][j] = z; }

  auto stage = [&](unsigned short* base, int it) {
    const unsigned short* aslab = Pb + ((size_t)qt * 16 + it) * 2048;
    gload_lds16(aslab + swz(tid) * 8, base + tid * 8);
    const unsigned short* bslab = Vt + ((size_t)blk * 16 + it) * 16384;
#pragma unroll
    for (int h = 0; h < 8; ++h) {
      const int c = tid + h * 256;
      gload_lds16(bslab + swz(c) * 8, base + 2048 + c * 8);
    }
  };

  stage(smem, 0);
  __syncthreads();
  int cur = 0;
  for (int it = 0; it < 16; ++it) {
    unsigned short* cbuf = smem + cur * 18432;
    if (it < 15) stage(smem + (cur ^ 1) * 18432, it + 1);
    const unsigned short* As = cbuf;
    const unsigned short* Bs = cbuf + 2048;
    short8 af[4], bfv[8];
#pragma unroll
    for (int i = 0; i < 4; ++i)
      af[i] = *(const short8*)&As[(i * 16 + l16) * 32 + qx * 8];
#pragma unroll
    for (int j = 0; j < 8; ++j)
      bfv[j] = *(const short8*)&Bs[(wv * 128 + j * 16 + l16) * 32 + qx * 8];
#pragma unroll
    for (int i = 0; i < 4; ++i)
#pragma unroll
      for (int j = 0; j < 8; ++j)
        acc[i][j] = __builtin_amdgcn_mfma_f32_16x16x32_bf16(
            af[i], bfv[j], acc[i][j], 0, 0, 0);
    __syncthreads();
    cur ^= 1;
  }

  float vsum[4][4], vsq[4][4];
#pragma unroll
  for (int i = 0; i < 4; ++i)
#pragma unroll
    for (int r = 0; r < 4; ++r) { vsum[i][r] = 0.f; vsq[i][r] = 0.f; }
#pragma unroll
  for (int i = 0; i < 4; ++i)
#pragma unroll
    for (int j = 0; j < 8; ++j)
#pragma unroll
      for (int r = 0; r < 4; ++r) {
        const int tok = (int)(q0 + i * 16 + quad * 4 + r);
        const int col = wv * 128 + j * 16 + l16;
        const float v = acc[i][j][r] +
            bf2f(Xb[((size_t)(tok >> 7) * 16 + (col >> 5)) * 4096 +
                    (tok & 127) * 32 + (col & 31)]);
        acc[i][j][r] = v;
        vsum[i][r] += v;
        vsq[i][r] += v * v;
      }
#pragma unroll
  for (int i = 0; i < 4; ++i)
#pragma unroll
    for (int r = 0; r < 4; ++r)
      for (int d = 1; d < 16; d <<= 1) {
        vsum[i][r] += __shfl_xor(vsum[i][r], d, 64);
        vsq[i][r]  += __shfl_xor(vsq[i][r], d, 64);
      }
  if (l16 == 0)
#pragma unroll
    for (int i = 0; i < 4; ++i)
#pragma unroll
      for (int r = 0; r < 4; ++r) {
        float2 p; p.x = vsum[i][r]; p.y = vsq[i][r];
        red[wv][i * 16 + quad * 4 + r] = p;
      }
  __syncthreads();
#pragma unroll
  for (int i = 0; i < 4; ++i)
#pragma unroll
    for (int r = 0; r < 4; ++r) {
      const int row = i * 16 + quad * 4 + r;
      float s = 0.f, q = 0.f;
#pragma unroll
      for (int w = 0; w < 4; ++w) { s += red[w][row].x; q += red[w][row].y; }
      const float mean = s * (1.0f / 512.0f);
      const float var  = q * (1.0f / 512.0f) - mean * mean;
      vsum[i][r] = mean;
      vsq[i][r]  = rsqrtf(var + 1e-3f);
    }
  // ---- Out repack: float L[64][260] (66.5 KB; stride 260: quad*4*260
  // mod 32 = 16 -> 2-way = free), two col-halves ----
  float* L = (float*)smem;
#pragma unroll
  for (int p = 0; p < 2; ++p) {
    __syncthreads();                       // previous pass reads done
    if ((wv >> 1) == p) {                  // waves owning cols [p*256, p*256+256)
#pragma unroll
      for (int i = 0; i < 4; ++i)
#pragma unroll
        for (int j = 0; j < 8; ++j) {
          const int cl = (wv & 1) * 128 + j * 16 + l16;
          const int t0 = i * 16 + quad * 4;
#pragma unroll
          for (int r = 0; r < 4; ++r)
            L[(t0 + r) * 260 + cl] = (acc[i][j][r] - vsum[i][r]) * vsq[i][r];
        }
    }
    __syncthreads();
#pragma unroll
    for (int h = 0; h < 16; ++h) {
      const int c = tid + h * 256;         // 4096 float4 chunks (64x256)
      const int tl = c >> 6, c0 = (c & 63) * 4;
      const float4 v = *(const float4*)&L[tl * 260 + c0];
      *(float4*)&Out[(q0 + tl) * (size_t)DIMK + p * 256 + c0] = v;
    }
  }
}

// ---------------------------------------------------------------------------
extern "C" void kernel_launch(void* const* d_in, const int* in_sizes, int n_in,
                              void* d_out, int out_size, void* d_ws, size_t ws_size,
                              hipStream_t stream)
{
  const float* X    = (const float*)d_in[0];
  const float* mask = (const float*)d_in[1];
  const float* dw1  = (const float*)d_in[2];
  const float* dw2  = (const float*)d_in[3];
  const float* dw3  = (const float*)d_in[4];
  const float* db1  = (const float*)d_in[5];
  const float* db2  = (const float*)d_in[6];
  const float* db3  = (const float*)d_in[7];
  float* Out = (float*)d_out;

  char* ws = (char*)d_ws;
  const size_t MB = 1ull << 20;
  // ws (130 MB): [Wt 2 | Qb/Pb 32 | Kb 32 | Vt 32 | Xb 32]
  // bits (2.1 MB) live in d_out's head: written by k_prep, consumed by
  // k_attn_p, then d_out fully overwritten by k_pv_ln (stream-ordered).
  unsigned short* Wt = (unsigned short*)(ws);
  unsigned short* Qb = (unsigned short*)(ws + 2 * MB);
  unsigned short* Kb = (unsigned short*)(ws + 34 * MB);
  unsigned short* Vt = (unsigned short*)(ws + 66 * MB);
  unsigned short* Xb = (unsigned short*)(ws + 98 * MB);
  unsigned short* Pb = Qb;                      // alias: safe (own-rows only)
  unsigned char*  bits = (unsigned char*)d_out;

  k_prep   <<<16576, 256, 0, stream>>>(X, mask, dw1, dw2, dw3, Xb, bits, Wt);
  k_qkv    <<<1024, 256, 0, stream>>>(Xb, Wt, db1, db2, db3, Qb, Kb, Vt);
  k_attn_p <<<512, 256, 0, stream>>>(Qb, Kb, (const unsigned long long*)bits, Pb);
  k_pv_ln  <<<512, 256, 0, stream>>>(Pb, Vt, Xb, Out);
}